// Round 12
// baseline (256.355 us; speedup 1.0000x reference)
//
#include <hip/hip_runtime.h>
#include <hip/hip_bf16.h>

#define IN_CH 128
#define SCAN_B 256

typedef __attribute__((ext_vector_type(8))) short bf16x8;
typedef __attribute__((ext_vector_type(4))) float f32x4;

__device__ __forceinline__ ushort f2bf(float f) {
    uint u = __float_as_uint(f);
    uint r = (u + 0x7fffu + ((u >> 16) & 1u)) >> 16;  // RNE
    return (ushort)r;
}
__device__ __forceinline__ float bflo(uint u) { return __uint_as_float(u << 16); }
__device__ __forceinline__ float bfhi(uint u) { return __uint_as_float(u & 0xffff0000u); }

// ---------------------------------------------------------------------------
// Fused prep: [count_deg blocks] [x->bf16 blocks] [W transpose blocks]
// ---------------------------------------------------------------------------

__global__ __launch_bounds__(256) void prep_count_kernel(
    const int* __restrict__ ei, int* __restrict__ deg,
    const float* __restrict__ x, ushort* __restrict__ xb,
    const float* __restrict__ W1l, const float* __restrict__ W1r,
    const float* __restrict__ W2l, const float* __restrict__ W2r,
    ushort* __restrict__ W1lT, ushort* __restrict__ W1rT,
    ushort* __restrict__ W2lT, ushort* __restrict__ W2rT,
    int n_edges, int nx, int cnt_blocks, int cvt_blocks) {
    int b = blockIdx.x, tid = threadIdx.x;
    if (b < cnt_blocks) {
        int e4 = b * 256 + tid;
        if (e4 * 4 < n_edges) {
            int4 d = *(const int4*)(ei + n_edges + e4 * 4);  // dst row
            atomicAdd(&deg[d.x], 1);
            atomicAdd(&deg[d.y], 1);
            atomicAdd(&deg[d.z], 1);
            atomicAdd(&deg[d.w], 1);
        }
    } else if (b < cnt_blocks + cvt_blocks) {
        int i = (b - cnt_blocks) * 256 + tid;
        if (i * 8 < nx) {
            float4 v0 = *(const float4*)(x + i * 8);
            float4 v1 = *(const float4*)(x + i * 8 + 4);
            uint4 o;
            o.x = (uint)f2bf(v0.x) | ((uint)f2bf(v0.y) << 16);
            o.y = (uint)f2bf(v0.z) | ((uint)f2bf(v0.w) << 16);
            o.z = (uint)f2bf(v1.x) | ((uint)f2bf(v1.y) << 16);
            o.w = (uint)f2bf(v1.z) | ((uint)f2bf(v1.w) << 16);
            *(uint4*)(xb + i * 8) = o;
        }
    } else {
        int t = (b - cnt_blocks - cvt_blocks) * 256 + tid;
        if (t < 16384) {                       // W1l^T  [128][128]
            int nn = t >> 7, kk = t & 127;
            W1lT[t] = f2bf(W1l[kk * 128 + nn]);
        } else if (t < 32768) {                // W1r^T
            int u = t - 16384;
            int nn = u >> 7, kk = u & 127;
            W1rT[u] = f2bf(W1r[kk * 128 + nn]);
        } else if (t < 40960) {                // W2l^T  [64][128]
            int u = t - 32768;
            int nn = u >> 7, kk = u & 127;
            W2lT[u] = f2bf(W2l[kk * 64 + nn]);
        } else if (t < 49152) {                // W2r^T
            int u = t - 40960;
            int nn = u >> 7, kk = u & 127;
            W2rT[u] = f2bf(W2r[kk * 64 + nn]);
        }
    }
}

// ---------------------------------------------------------------------------
// Scan: per-chunk partial sums, then per-chunk scan with redundant LDS base
// scan of the partials (nsb <= 256), writing offsets & cursor.
// ---------------------------------------------------------------------------

__global__ __launch_bounds__(SCAN_B) void scan_partials_kernel(
    const int* __restrict__ deg, int* __restrict__ partials, int n) {
    __shared__ int ws[SCAN_B / 64];
    int i = blockIdx.x * SCAN_B + threadIdx.x;
    int v = (i < n) ? deg[i] : 0;
    for (int off = 32; off > 0; off >>= 1) v += __shfl_down(v, off, 64);
    int lane = threadIdx.x & 63, w = threadIdx.x >> 6;
    if (lane == 0) ws[w] = v;
    __syncthreads();
    if (threadIdx.x == 0) {
        int s = 0;
        for (int k = 0; k < SCAN_B / 64; ++k) s += ws[k];
        partials[blockIdx.x] = s;
    }
}

__global__ __launch_bounds__(SCAN_B) void scan_final_kernel(
    const int* __restrict__ deg, const int* __restrict__ partials,
    int* __restrict__ offsets, int* __restrict__ cursor, int n, int nsb) {
    __shared__ int sA[SCAN_B];
    __shared__ int sB[SCAN_B];
    int t = threadIdx.x;
    sA[t] = (t < nsb) ? partials[t] : 0;
    __syncthreads();
    for (int m = 1; m < SCAN_B; m <<= 1) {
        int u = (t >= m) ? sA[t - m] : 0;
        __syncthreads();
        sA[t] += u;
        __syncthreads();
    }
    int base  = (blockIdx.x > 0) ? sA[blockIdx.x - 1] : 0;
    int total = sA[nsb - 1];
    int i = blockIdx.x * SCAN_B + t;
    int v = (i < n) ? deg[i] : 0;
    sB[t] = v;
    __syncthreads();
    for (int m = 1; m < SCAN_B; m <<= 1) {
        int u = (t >= m) ? sB[t - m] : 0;
        __syncthreads();
        sB[t] += u;
        __syncthreads();
    }
    if (i < n) {
        int o = base + sB[t] - v;
        offsets[i] = o;
        cursor[i]  = o;
    }
    if (blockIdx.x == 0 && t == 0) offsets[n] = total;
}

__global__ __launch_bounds__(256) void fill_kernel(
    const int* __restrict__ ei, int* __restrict__ cursor,
    int* __restrict__ edge_src, int n_edges) {
    int e4 = blockIdx.x * 256 + threadIdx.x;
    if (e4 * 4 >= n_edges) return;
    int4 s = *(const int4*)(ei + e4 * 4);
    int4 d = *(const int4*)(ei + n_edges + e4 * 4);
    edge_src[atomicAdd(&cursor[d.x], 1)] = s.x;
    edge_src[atomicAdd(&cursor[d.y], 1)] = s.y;
    edge_src[atomicAdd(&cursor[d.z], 1)] = s.z;
    edge_src[atomicAdd(&cursor[d.w], 1)] = s.w;
}

// ---------------------------------------------------------------------------
// Gather-side mean, 128-dim rows (256B): one wave/node, 16 lanes/row.
// BRANCH-FREE 6-deep load pipeline (24 edges): clamped indices + value mask
// -> 6 independent idx->row chains in flight (was ~2, latency-bound).
// deg > 24 (P ~ 0.1% at mean-12) falls to the loop.
// ---------------------------------------------------------------------------

__global__ __launch_bounds__(256) void gather_mean128_kernel(
    const ushort* __restrict__ feat, const int* __restrict__ offsets,
    const int* __restrict__ edge_src, ushort* __restrict__ mean,
    int n_nodes, int n_edges) {
    int wid  = (blockIdx.x * blockDim.x + threadIdx.x) >> 6;
    int lane = threadIdx.x & 63;
    if (wid >= n_nodes) return;
    int beg = offsets[wid];
    int end = offsets[wid + 1];
    int q = lane >> 4;
    int c = lane & 15;
    float s0 = 0, s1 = 0, s2 = 0, s3 = 0, s4 = 0, s5 = 0, s6 = 0, s7 = 0;

    int lastc = min(max(end - 1, 0), n_edges - 1);  // safe clamp (deg==0 ok)
    int base = beg + q;

#pragma unroll
    for (int i = 0; i < 6; ++i) {
        int eidx = base + i * 4;
        int ridx = edge_src[min(eidx, lastc)];
        uint4 A = *(const uint4*)(feat + (size_t)ridx * 128 + c * 8);
        if (eidx < end) {
            s0 += bflo(A.x);  s1 += bfhi(A.x);
            s2 += bflo(A.y);  s3 += bfhi(A.y);
            s4 += bflo(A.z);  s5 += bfhi(A.z);
            s6 += bflo(A.w);  s7 += bfhi(A.w);
        }
    }
    for (int e = beg + 24; e + q < end; e += 4) {   // rare tail
        int ridx = edge_src[e + q];
        uint4 A = *(const uint4*)(feat + (size_t)ridx * 128 + c * 8);
        s0 += bflo(A.x);  s1 += bfhi(A.x);
        s2 += bflo(A.y);  s3 += bfhi(A.y);
        s4 += bflo(A.z);  s5 += bfhi(A.z);
        s6 += bflo(A.w);  s7 += bfhi(A.w);
    }

#pragma unroll
    for (int m = 16; m < 64; m <<= 1) {
        s0 += __shfl_xor(s0, m, 64);
        s1 += __shfl_xor(s1, m, 64);
        s2 += __shfl_xor(s2, m, 64);
        s3 += __shfl_xor(s3, m, 64);
        s4 += __shfl_xor(s4, m, 64);
        s5 += __shfl_xor(s5, m, 64);
        s6 += __shfl_xor(s6, m, 64);
        s7 += __shfl_xor(s7, m, 64);
    }

    if (q == 0) {
        float inv = 1.0f / fmaxf((float)(end - beg), 1.0f);
        uint4 o;
        o.x = (uint)f2bf(s0 * inv) | ((uint)f2bf(s1 * inv) << 16);
        o.y = (uint)f2bf(s2 * inv) | ((uint)f2bf(s3 * inv) << 16);
        o.z = (uint)f2bf(s4 * inv) | ((uint)f2bf(s5 * inv) << 16);
        o.w = (uint)f2bf(s6 * inv) | ((uint)f2bf(s7 * inv) << 16);
        *(uint4*)(mean + (size_t)wid * 128 + c * 8) = o;
    }
}

// ---------------------------------------------------------------------------
// Gather-side mean, 64-dim rows (128B): 8 lanes/row, 8 rows per instruction.
// Branch-free 3-deep pipeline (24 edges), same masking scheme.
// ---------------------------------------------------------------------------

__global__ __launch_bounds__(256) void gather_mean64_kernel(
    const ushort* __restrict__ feat, const int* __restrict__ offsets,
    const int* __restrict__ edge_src, ushort* __restrict__ mean,
    int n_nodes, int n_edges) {
    int wid  = (blockIdx.x * blockDim.x + threadIdx.x) >> 6;
    int lane = threadIdx.x & 63;
    if (wid >= n_nodes) return;
    int beg = offsets[wid];
    int end = offsets[wid + 1];
    int q = lane >> 3;   // 0..7
    int c = lane & 7;
    float s0 = 0, s1 = 0, s2 = 0, s3 = 0, s4 = 0, s5 = 0, s6 = 0, s7 = 0;

    int lastc = min(max(end - 1, 0), n_edges - 1);
    int base = beg + q;

#pragma unroll
    for (int i = 0; i < 3; ++i) {
        int eidx = base + i * 8;
        int ridx = edge_src[min(eidx, lastc)];
        uint4 A = *(const uint4*)(feat + (size_t)ridx * 64 + c * 8);
        if (eidx < end) {
            s0 += bflo(A.x);  s1 += bfhi(A.x);
            s2 += bflo(A.y);  s3 += bfhi(A.y);
            s4 += bflo(A.z);  s5 += bfhi(A.z);
            s6 += bflo(A.w);  s7 += bfhi(A.w);
        }
    }
    for (int e = beg + 24; e + q < end; e += 8) {   // rare tail
        int ridx = edge_src[e + q];
        uint4 A = *(const uint4*)(feat + (size_t)ridx * 64 + c * 8);
        s0 += bflo(A.x);  s1 += bfhi(A.x);
        s2 += bflo(A.y);  s3 += bfhi(A.y);
        s4 += bflo(A.z);  s5 += bfhi(A.z);
        s6 += bflo(A.w);  s7 += bfhi(A.w);
    }

#pragma unroll
    for (int m = 8; m < 64; m <<= 1) {
        s0 += __shfl_xor(s0, m, 64);
        s1 += __shfl_xor(s1, m, 64);
        s2 += __shfl_xor(s2, m, 64);
        s3 += __shfl_xor(s3, m, 64);
        s4 += __shfl_xor(s4, m, 64);
        s5 += __shfl_xor(s5, m, 64);
        s6 += __shfl_xor(s6, m, 64);
        s7 += __shfl_xor(s7, m, 64);
    }

    if (q == 0) {
        float inv = 1.0f / fmaxf((float)(end - beg), 1.0f);
        uint4 o;
        o.x = (uint)f2bf(s0 * inv) | ((uint)f2bf(s1 * inv) << 16);
        o.y = (uint)f2bf(s2 * inv) | ((uint)f2bf(s3 * inv) << 16);
        o.z = (uint)f2bf(s4 * inv) | ((uint)f2bf(s5 * inv) << 16);
        o.w = (uint)f2bf(s6 * inv) | ((uint)f2bf(s7 * inv) << 16);
        *(uint4*)(mean + (size_t)wid * 64 + c * 8) = o;
    }
}

// ---------------------------------------------------------------------------
// Layer 1 (MFMA): h = relu(mean @ W1l + x @ W1r + b1), bf16 in/out.
// ---------------------------------------------------------------------------

__global__ __launch_bounds__(256) void l1_mfma_kernel(
    const ushort* __restrict__ mean, const ushort* __restrict__ xb,
    const ushort* __restrict__ WlT, const ushort* __restrict__ WrT,
    const float* __restrict__ b, ushort* __restrict__ h, int n_nodes) {
    int wave = threadIdx.x >> 6, lane = threadIdx.x & 63;
    int m0 = (blockIdx.x * 4 + wave) * 32;
    int r  = lane & 15;
    int ko = (lane >> 4) * 8;

    int gc0 = min(m0 + r,      n_nodes - 1);
    int gc1 = min(m0 + 16 + r, n_nodes - 1);

    f32x4 acc[8][2] = {};
#pragma unroll
    for (int kk = 0; kk < 4; ++kk) {
        int kb = kk * 32 + ko;
        bf16x8 aM0 = *(const bf16x8*)(mean + (size_t)gc0 * 128 + kb);
        bf16x8 aM1 = *(const bf16x8*)(mean + (size_t)gc1 * 128 + kb);
        bf16x8 aX0 = *(const bf16x8*)(xb   + (size_t)gc0 * 128 + kb);
        bf16x8 aX1 = *(const bf16x8*)(xb   + (size_t)gc1 * 128 + kb);
#pragma unroll
        for (int j = 0; j < 8; ++j) {
            bf16x8 bL = *(const bf16x8*)(WlT + (size_t)(j * 16 + r) * 128 + kb);
            bf16x8 bR = *(const bf16x8*)(WrT + (size_t)(j * 16 + r) * 128 + kb);
            acc[j][0] = __builtin_amdgcn_mfma_f32_16x16x32_bf16(aM0, bL, acc[j][0], 0, 0, 0);
            acc[j][0] = __builtin_amdgcn_mfma_f32_16x16x32_bf16(aX0, bR, acc[j][0], 0, 0, 0);
            acc[j][1] = __builtin_amdgcn_mfma_f32_16x16x32_bf16(aM1, bL, acc[j][1], 0, 0, 0);
            acc[j][1] = __builtin_amdgcn_mfma_f32_16x16x32_bf16(aX1, bR, acc[j][1], 0, 0, 0);
        }
    }

#pragma unroll
    for (int j = 0; j < 8; ++j) {
        float bv = b[j * 16 + r];
#pragma unroll
        for (int s = 0; s < 2; ++s) {
            int rowbase = m0 + s * 16 + (lane >> 4) * 4;
#pragma unroll
            for (int q = 0; q < 4; ++q) {
                int g = rowbase + q;
                if (g < n_nodes)
                    h[(size_t)g * 128 + j * 16 + r] =
                        f2bf(fmaxf(acc[j][s][q] + bv, 0.f));
            }
        }
    }
}

// ---------------------------------------------------------------------------
// Layer 2a (MFMA): hp = bf16(h @ W2l)  [n,64]  (projection BEFORE the gather)
// ---------------------------------------------------------------------------

__global__ __launch_bounds__(256) void l2p_mfma_kernel(
    const ushort* __restrict__ hb, const ushort* __restrict__ WlT,
    ushort* __restrict__ hp, int n_nodes) {
    int wave = threadIdx.x >> 6, lane = threadIdx.x & 63;
    int m0 = (blockIdx.x * 4 + wave) * 32;
    int r  = lane & 15;
    int ko = (lane >> 4) * 8;

    int gc0 = min(m0 + r,      n_nodes - 1);
    int gc1 = min(m0 + 16 + r, n_nodes - 1);

    f32x4 acc[4][2] = {};
#pragma unroll
    for (int kk = 0; kk < 4; ++kk) {
        int kb = kk * 32 + ko;
        bf16x8 aH0 = *(const bf16x8*)(hb + (size_t)gc0 * 128 + kb);
        bf16x8 aH1 = *(const bf16x8*)(hb + (size_t)gc1 * 128 + kb);
#pragma unroll
        for (int j = 0; j < 4; ++j) {
            bf16x8 bL = *(const bf16x8*)(WlT + (size_t)(j * 16 + r) * 128 + kb);
            acc[j][0] = __builtin_amdgcn_mfma_f32_16x16x32_bf16(aH0, bL, acc[j][0], 0, 0, 0);
            acc[j][1] = __builtin_amdgcn_mfma_f32_16x16x32_bf16(aH1, bL, acc[j][1], 0, 0, 0);
        }
    }
#pragma unroll
    for (int j = 0; j < 4; ++j) {
#pragma unroll
        for (int s = 0; s < 2; ++s) {
            int rowbase = m0 + s * 16 + (lane >> 4) * 4;
#pragma unroll
            for (int q = 0; q < 4; ++q) {
                int g = rowbase + q;
                if (g < n_nodes)
                    hp[(size_t)g * 64 + j * 16 + r] = f2bf(acc[j][s][q]);
            }
        }
    }
}

// ---------------------------------------------------------------------------
// Layer 2b (MFMA): out = m2 + h @ W2r + b2, fp32 output [n,64].
// ---------------------------------------------------------------------------

__global__ __launch_bounds__(256) void l2r_mfma_kernel(
    const ushort* __restrict__ hb, const ushort* __restrict__ WrT,
    const ushort* __restrict__ m2, const float* __restrict__ b,
    float* __restrict__ out, int n_nodes) {
    int wave = threadIdx.x >> 6, lane = threadIdx.x & 63;
    int m0 = (blockIdx.x * 4 + wave) * 32;
    int r  = lane & 15;
    int ko = (lane >> 4) * 8;

    int gc0 = min(m0 + r,      n_nodes - 1);
    int gc1 = min(m0 + 16 + r, n_nodes - 1);

    f32x4 acc[4][2] = {};
#pragma unroll
    for (int kk = 0; kk < 4; ++kk) {
        int kb = kk * 32 + ko;
        bf16x8 aH0 = *(const bf16x8*)(hb + (size_t)gc0 * 128 + kb);
        bf16x8 aH1 = *(const bf16x8*)(hb + (size_t)gc1 * 128 + kb);
#pragma unroll
        for (int j = 0; j < 4; ++j) {
            bf16x8 bR = *(const bf16x8*)(WrT + (size_t)(j * 16 + r) * 128 + kb);
            acc[j][0] = __builtin_amdgcn_mfma_f32_16x16x32_bf16(aH0, bR, acc[j][0], 0, 0, 0);
            acc[j][1] = __builtin_amdgcn_mfma_f32_16x16x32_bf16(aH1, bR, acc[j][1], 0, 0, 0);
        }
    }
#pragma unroll
    for (int j = 0; j < 4; ++j) {
        float bv = b[j * 16 + r];
#pragma unroll
        for (int s = 0; s < 2; ++s) {
            int rowbase = m0 + s * 16 + (lane >> 4) * 4;
#pragma unroll
            for (int q = 0; q < 4; ++q) {
                int g = rowbase + q;
                if (g < n_nodes) {
                    float mv = __uint_as_float((uint)m2[(size_t)g * 64 + j * 16 + r] << 16);
                    out[(size_t)g * 64 + j * 16 + r] = acc[j][s][q] + bv + mv;
                }
            }
        }
    }
}

// ---------------------------------------------------------------------------

extern "C" void kernel_launch(void* const* d_in, const int* in_sizes, int n_in,
                              void* d_out, int out_size, void* d_ws, size_t ws_size,
                              hipStream_t stream) {
    const float* x   = (const float*)d_in[0];
    const int*   ei  = (const int*)d_in[1];
    const float* W1l = (const float*)d_in[2];
    const float* W1r = (const float*)d_in[3];
    const float* b1  = (const float*)d_in[4];
    const float* W2l = (const float*)d_in[5];
    const float* W2r = (const float*)d_in[6];
    const float* b2  = (const float*)d_in[7];
    float* out = (float*)d_out;

    int n_nodes = in_sizes[0] / IN_CH;
    int n_edges = in_sizes[1] / 2;
    int nsb = (n_nodes + SCAN_B - 1) / SCAN_B;   // 196 (<=256 required)

    // Workspace layout
    char* ws = (char*)d_ws;
    int* deg      = (int*)ws;                    // n
    int* offsets  = deg + n_nodes;               // n+1
    int* cursor   = offsets + n_nodes + 1;       // n
    int* partials = cursor + n_nodes;            // nsb
    int* edge_src = partials + nsb;              // E
    size_t off = ((size_t)(3 * n_nodes + 1 + nsb + n_edges)) * sizeof(int);
    off = (off + 255) & ~(size_t)255;
    ushort* xb    = (ushort*)(ws + off);             // n*128 bf16
    ushort* meanb = xb    + (size_t)n_nodes * 128;   // n*128 bf16 (layer-1 mean)
    ushort* hb    = meanb + (size_t)n_nodes * 128;   // n*128 bf16
    ushort* hp    = hb    + (size_t)n_nodes * 128;   // n*64  bf16 (h @ W2l)
    ushort* m2    = hp    + (size_t)n_nodes * 64;    // n*64  bf16 (mean of hp)
    ushort* W1lT  = m2    + (size_t)n_nodes * 64;    // 128*128
    ushort* W1rT  = W1lT + 128 * 128;
    ushort* W2lT  = W1rT + 128 * 128;                // 64*128
    ushort* W2rT  = W2lT + 64 * 128;

    hipMemsetAsync(deg, 0, n_nodes * sizeof(int), stream);

    const int TB = 256;
    int nx = n_nodes * IN_CH;
    int cnt_blocks = (n_edges / 4 + TB - 1) / TB;
    int cvt_blocks = (nx / 8 + TB - 1) / TB;
    int tr_blocks  = (49152 + TB - 1) / TB;

    prep_count_kernel<<<cnt_blocks + cvt_blocks + tr_blocks, TB, 0, stream>>>(
        ei, deg, x, xb, W1l, W1r, W2l, W2r, W1lT, W1rT, W2lT, W2rT,
        n_edges, nx, cnt_blocks, cvt_blocks);
    scan_partials_kernel<<<nsb, SCAN_B, 0, stream>>>(deg, partials, n_nodes);
    scan_final_kernel<<<nsb, SCAN_B, 0, stream>>>(deg, partials, offsets, cursor,
                                                  n_nodes, nsb);
    fill_kernel<<<cnt_blocks, TB, 0, stream>>>(ei, cursor, edge_src, n_edges);

    int gblocks = (n_nodes * 64 + TB - 1) / TB;      // one wave per node
    int mblocks = (n_nodes + 127) / 128;             // 4 waves x 32 rows

    // Layer 1
    gather_mean128_kernel<<<gblocks, TB, 0, stream>>>(xb, offsets, edge_src, meanb,
                                                      n_nodes, n_edges);
    l1_mfma_kernel<<<mblocks, 256, 0, stream>>>(meanb, xb, W1lT, W1rT, b1, hb, n_nodes);

    // Layer 2: project first (hp = h@W2l), gather 64-dim, then fuse the rest
    l2p_mfma_kernel<<<mblocks, 256, 0, stream>>>(hb, W2lT, hp, n_nodes);
    gather_mean64_kernel<<<gblocks, TB, 0, stream>>>(hp, offsets, edge_src, m2,
                                                     n_nodes, n_edges);
    l2r_mfma_kernel<<<mblocks, 256, 0, stream>>>(hb, W2rT, m2, b2, out, n_nodes);
}